// Round 2
// baseline (398.761 us; speedup 1.0000x reference)
//
#include <hip/hip_runtime.h>
#include <cmath>

#define Bdim 8
#define Cdim 768
#define Kdim 256
#define Ndim 4096
#define NT 32      // tokens per block in kernel 1
#define KC 16      // C-chunk staged in LDS
#define CB 8       // c-rows per block in kernel 2

// Kernel 1: per (b, n-tile of 32): cos over all K=256 centroids (fp32 register
// GEMM), per-k sigmoid, first-win argmax, dense sim_masked tile write
// (zeros + winner -> absorbs the 128 MB memset), counts, (w, k*) arrays.
__global__ __launch_bounds__(256) void sim_argmax_kernel(
    const float* __restrict__ x,        // (B,C,N)
    const float* __restrict__ cents,    // (B,C,K)
    const float* __restrict__ alpha_p,
    const float* __restrict__ beta_p,
    float* __restrict__ simOut,         // (B,K,N) fully written here
    float* __restrict__ wArr,           // (B,N)
    int*   __restrict__ kArr,           // (B,N)
    int*   __restrict__ cnt)            // (B,K), pre-zeroed
{
    __shared__ float sc[KC][Kdim];      // 16 KB centroid chunk
    __shared__ float sx[KC][NT];        // 2 KB  x chunk
    __shared__ float invc[Kdim];        // 1 KB
    __shared__ float px[8][NT];         // 1 KB
    __shared__ float invx[NT];
    __shared__ float bval[32][NT];      // 4 KB per-kgroup best sim
    __shared__ int   bidx[32][NT];      // 4 KB per-kgroup best k
    __shared__ float wbestS[NT];
    __shared__ int   kstarS[NT];

    const int tid = threadIdx.x;
    const int b   = blockIdx.x >> 7;            // 128 n-tiles per batch
    const int n0  = (blockIdx.x & 127) * NT;
    const float* xb = x     + (size_t)b * Cdim * Ndim;
    const float* cb = cents + (size_t)b * Cdim * Kdim;

    const int kb = (tid >> 3) * 8;      // 8 consecutive k per thread
    const int nb = (tid & 7) * 4;       // 4 consecutive n per thread

    float acc[8][4];
    #pragma unroll
    for (int i = 0; i < 8; ++i)
        #pragma unroll
        for (int j = 0; j < 4; ++j) acc[i][j] = 0.f;

    float cn2  = 0.f;   // thread t accumulates ||centroid k=t||^2
    float xn2p = 0.f;   // partial ||x_n||^2 (group tid>>5, token tid&31)

    // register prefetch buffers (double-buffer the LDS staging)
    float4 rA[4];
    float4 rB;

    {   // prefetch chunk 0
        #pragma unroll
        for (int i = 0; i < 4; ++i) {
            int idx = tid + i * 256, r = idx >> 6, c4 = idx & 63;
            rA[i] = *(const float4*)(cb + (size_t)r * Kdim + c4 * 4);
        }
        if (tid < 128) {
            int r = tid >> 3, c4 = tid & 7;
            rB = *(const float4*)(xb + (size_t)r * Ndim + n0 + c4 * 4);
        }
    }

    for (int c0 = 0; c0 < Cdim; c0 += KC) {
        __syncthreads();     // previous chunk's consumers done
        #pragma unroll
        for (int i = 0; i < 4; ++i) {
            int idx = tid + i * 256;
            *(float4*)&sc[idx >> 6][(idx & 63) * 4] = rA[i];
        }
        if (tid < 128) *(float4*)&sx[tid >> 3][(tid & 7) * 4] = rB;
        __syncthreads();

        if (c0 + KC < Cdim) {   // prefetch next chunk into registers
            #pragma unroll
            for (int i = 0; i < 4; ++i) {
                int idx = tid + i * 256, r = idx >> 6, c4 = idx & 63;
                rA[i] = *(const float4*)(cb + (size_t)(c0 + KC + r) * Kdim + c4 * 4);
            }
            if (tid < 128) {
                int r = tid >> 3, c4 = tid & 7;
                rB = *(const float4*)(xb + (size_t)(c0 + KC + r) * Ndim + n0 + c4 * 4);
            }
        }

        // norms from staged tiles
        #pragma unroll
        for (int r = 0; r < KC; ++r) { float v = sc[r][tid]; cn2 = fmaf(v, v, cn2); }
        {
            int r0 = (tid >> 5) * 2;
            float v0 = sx[r0][tid & 31];     xn2p = fmaf(v0, v0, xn2p);
            float v1 = sx[r0 + 1][tid & 31]; xn2p = fmaf(v1, v1, xn2p);
        }

        // main 8x4 FMA tile
        #pragma unroll
        for (int r = 0; r < KC; ++r) {
            float a0[8], b0[4];
            *(float4*)(a0)     = *(const float4*)&sc[r][kb];
            *(float4*)(a0 + 4) = *(const float4*)&sc[r][kb + 4];
            *(float4*)(b0)     = *(const float4*)&sx[r][nb];
            #pragma unroll
            for (int i = 0; i < 8; ++i)
                #pragma unroll
                for (int j = 0; j < 4; ++j)
                    acc[i][j] = fmaf(a0[i], b0[j], acc[i][j]);
        }
    }

    invc[tid] = 1.f / fmaxf(sqrtf(cn2), 1e-12f);
    px[tid >> 5][tid & 31] = xn2p;
    __syncthreads();
    if (tid < NT) {
        float s = 0.f;
        #pragma unroll
        for (int g = 0; g < 8; ++g) s += px[g][tid];
        invx[tid] = 1.f / fmaxf(sqrtf(s), 1e-12f);
    }
    __syncthreads();

    const float alpha = alpha_p[0];
    const float beta  = beta_p[0];

    // per-thread argmax over its 8 k (ascending k, strict > = first-win)
    #pragma unroll
    for (int j = 0; j < 4; ++j) {
        int n = nb + j;
        float ix = invx[n];
        float best = -1.f; int bkk = 0;
        #pragma unroll
        for (int i = 0; i < 8; ++i) {
            float cosv = acc[i][j] * invc[kb + i] * ix;
            float s = 1.f / (1.f + expf(-(beta + alpha * cosv)));
            if (s > best) { best = s; bkk = kb + i; }
        }
        bval[tid >> 3][n] = best;
        bidx[tid >> 3][n] = bkk;
    }
    __syncthreads();
    if (tid < NT) {
        int n = tid;
        float best = -1.f; int bkk = 0;
        for (int g = 0; g < 32; ++g) {   // ascending k-groups = first-win
            float v = bval[g][n];
            if (v > best) { best = v; bkk = bidx[g][n]; }
        }
        int gn = b * Ndim + n0 + n;
        wArr[gn] = best;
        kArr[gn] = bkk;
        wbestS[n] = best;
        kstarS[n] = bkk;
        atomicAdd(&cnt[b * Kdim + bkk], 1);
    }
    __syncthreads();

    // dense sim_masked tile write: zeros everywhere except each token's winner
    #pragma unroll
    for (int i = 0; i < 8; ++i) {
        int k = kb + i;
        float4 v;
        v.x = (k == kstarS[nb + 0]) ? wbestS[nb + 0] : 0.f;
        v.y = (k == kstarS[nb + 1]) ? wbestS[nb + 1] : 0.f;
        v.z = (k == kstarS[nb + 2]) ? wbestS[nb + 2] : 0.f;
        v.w = (k == kstarS[nb + 3]) ? wbestS[nb + 3] : 0.f;
        *(float4*)&simOut[((size_t)(b * Kdim + k)) * Ndim + n0 + nb] = v;
    }
}

// Kernel 2: per (b, 8 c-rows): stream all N tokens (float4 coalesced),
// LDS-atomic scatter into accs[c][k], fused (agg + ct)/(cnt+1) epilogue.
__global__ __launch_bounds__(256) void agg_kernel(
    const float* __restrict__ x,        // (B,C,N)
    const float* __restrict__ cents,    // (B,C,K)
    const float* __restrict__ wArr,
    const int*   __restrict__ kArr,
    const int*   __restrict__ cnt,
    float* __restrict__ hyp)            // (B,K,C)
{
    __shared__ float accs[CB][Kdim + 1];  // pad 257: conflict-free transpose
    __shared__ float wS[Ndim];            // 16 KB
    __shared__ int   kS[Ndim];            // 16 KB
    const int tid = threadIdx.x;
    const int b  = blockIdx.x / (Cdim / CB);
    const int c0 = (blockIdx.x % (Cdim / CB)) * CB;

    for (int i = tid; i < CB * (Kdim + 1); i += 256) ((float*)accs)[i] = 0.f;
    #pragma unroll
    for (int i = 0; i < Ndim / 4 / 256; ++i) {     // 4 float4 / int4 each
        int i4 = tid + i * 256;
        *(float4*)&wS[i4 * 4] = *(const float4*)&wArr[b * Ndim + i4 * 4];
        *(int4*)&kS[i4 * 4]   = *(const int4*)&kArr[b * Ndim + i4 * 4];
    }
    __syncthreads();

    const float* xb = x + (size_t)b * Cdim * Ndim;
    for (int r = 0; r < CB; ++r) {
        const float* row = xb + (size_t)(c0 + r) * Ndim;
        #pragma unroll
        for (int i = 0; i < Ndim / 4 / 256; ++i) {
            int i4 = tid + i * 256;
            float4 v = *(const float4*)&row[i4 * 4];
            int n = i4 * 4;
            atomicAdd(&accs[r][kS[n + 0]], wS[n + 0] * v.x);
            atomicAdd(&accs[r][kS[n + 1]], wS[n + 1] * v.y);
            atomicAdd(&accs[r][kS[n + 2]], wS[n + 2] * v.z);
            atomicAdd(&accs[r][kS[n + 3]], wS[n + 3] * v.w);
        }
    }
    __syncthreads();

    // fused epilogue: hyp[b][k][c0+cl] = (accs[cl][k] + cents[b][c0+cl][k]) / (cnt+1)
    const int cl = tid & 7;
    #pragma unroll
    for (int it = 0; it < 8; ++it) {
        int k = (tid >> 3) + it * 32;
        float num = accs[cl][k] + cents[((size_t)b * Cdim + c0 + cl) * Kdim + k];
        hyp[((size_t)(b * Kdim + k)) * Cdim + c0 + cl] = num / (float)(cnt[b * Kdim + k] + 1);
    }
}

extern "C" void kernel_launch(void* const* d_in, const int* in_sizes, int n_in,
                              void* d_out, int out_size, void* d_ws, size_t ws_size,
                              hipStream_t stream)
{
    const float* x     = (const float*)d_in[0];
    const float* cents = (const float*)d_in[1];
    const float* alpha = (const float*)d_in[2];
    const float* beta  = (const float*)d_in[3];

    float* hyp    = (float*)d_out;                                    // (B,K,C)
    float* simOut = (float*)d_out + (size_t)Bdim * Kdim * Cdim;       // (B,K,N)

    float* wArr = (float*)d_ws;
    int*   kArr = (int*)((char*)d_ws + (size_t)Bdim * Ndim * sizeof(float));
    int*   cnt  = (int*)((char*)d_ws + 2 * (size_t)Bdim * Ndim * sizeof(float));

    hipMemsetAsync(cnt, 0, Bdim * Kdim * sizeof(int), stream);

    sim_argmax_kernel<<<dim3(Bdim * (Ndim / NT)), dim3(256), 0, stream>>>(
        x, cents, alpha, beta, simOut, wArr, kArr, cnt);
    agg_kernel<<<dim3(Bdim * (Cdim / CB)), dim3(256), 0, stream>>>(
        x, cents, wArr, kArr, cnt, hyp);
}

// Round 3
// 396.288 us; speedup vs baseline: 1.0062x; 1.0062x over previous
//
#include <hip/hip_runtime.h>
#include <cmath>

#define Bdim 8
#define Cdim 768
#define Kdim 256
#define Ndim 4096
#define NT 64      // tokens per block in kernel 1
#define KC 16      // C-chunk staged in LDS
#define CB 8       // c-rows per block in kernel 2

// Prep: per batch b — centroid inverse norms (hoisted out of k1) + zero cnt.
__global__ __launch_bounds__(256) void prep_kernel(
    const float* __restrict__ cents,   // (B,C,K)
    float* __restrict__ invc,          // (B,K)
    int*   __restrict__ cnt)           // (B,K)
{
    __shared__ float red[4][Kdim];
    const int tid = threadIdx.x;
    const int b = blockIdx.x;
    const float* cb = cents + (size_t)b * Cdim * Kdim;
    const int q = tid & 63;     // float4 column group (4 cols)
    const int g = tid >> 6;     // row group
    float4 ss = make_float4(0.f, 0.f, 0.f, 0.f);
    for (int r = g; r < Cdim; r += 4) {
        float4 v = *(const float4*)(cb + (size_t)r * Kdim + q * 4);
        ss.x = fmaf(v.x, v.x, ss.x); ss.y = fmaf(v.y, v.y, ss.y);
        ss.z = fmaf(v.z, v.z, ss.z); ss.w = fmaf(v.w, v.w, ss.w);
    }
    *(float4*)&red[g][q * 4] = ss;
    __syncthreads();
    float s = red[0][tid] + red[1][tid] + red[2][tid] + red[3][tid];
    invc[b * Kdim + tid] = 1.f / fmaxf(sqrtf(s), 1e-12f);
    cnt[b * Kdim + tid] = 0;
}

// Kernel 1: per (b, n-tile of 64): cos over all K=256 (fp32 register GEMM,
// 8x8/thread, LDS-broadcast operands), per-k sigmoid, first-win argmax,
// SCATTER write of sim_masked winner only (simOut pre-zeroed by memset).
__global__ __launch_bounds__(256) void sim_argmax_kernel(
    const float* __restrict__ x,        // (B,C,N)
    const float* __restrict__ cents,    // (B,C,K)
    const float* __restrict__ alpha_p,
    const float* __restrict__ beta_p,
    const float* __restrict__ invc,     // (B,K)
    float* __restrict__ simOut,         // (B,K,N), pre-zeroed
    float* __restrict__ wArr,           // (B,N)
    int*   __restrict__ kArr,           // (B,N)
    int*   __restrict__ cnt)            // (B,K), pre-zeroed
{
    __shared__ float sc[KC][Kdim];      // 16 KB centroid chunk
    __shared__ float sx[KC][NT];        // 4 KB  x chunk
    __shared__ float invcS[Kdim];       // 1 KB
    __shared__ float px[4][NT];         // 1 KB
    __shared__ float invxS[NT];
    __shared__ float bval[32][NT];      // 8 KB per-kgroup best sim
    __shared__ int   bidx[32][NT];      // 8 KB per-kgroup best k

    const int tid = threadIdx.x;
    const int b   = blockIdx.x >> 6;            // 64 n-tiles per batch
    const int n0  = (blockIdx.x & 63) * NT;
    const float* xb = x     + (size_t)b * Cdim * Ndim;
    const float* cb = cents + (size_t)b * Cdim * Kdim;

    invcS[tid] = invc[b * Kdim + tid];

    const int kb = (tid >> 3) * 8;      // 8 consecutive k per thread
    const int nb = (tid & 7) * 8;       // 8 consecutive n per thread

    float acc[8][8];
    #pragma unroll
    for (int i = 0; i < 8; ++i)
        #pragma unroll
        for (int j = 0; j < 8; ++j) acc[i][j] = 0.f;

    float xn2p = 0.f;   // partial ||x_n||^2 (rows (tid>>6)*4..+3, col tid&63)

    // register prefetch buffers (double-buffer the LDS staging)
    float4 rA[4];
    float4 rB;
    #pragma unroll
    for (int i = 0; i < 4; ++i) {       // chunk 0 centroid: 1024 float4
        int idx = tid + i * 256, r = idx >> 6, c4 = idx & 63;
        rA[i] = *(const float4*)(cb + (size_t)r * Kdim + c4 * 4);
    }
    {                                   // chunk 0 x: 256 float4
        int r = tid >> 4, c4 = tid & 15;
        rB = *(const float4*)(xb + (size_t)r * Ndim + n0 + c4 * 4);
    }

    for (int c0 = 0; c0 < Cdim; c0 += KC) {
        __syncthreads();     // previous chunk's consumers done
        #pragma unroll
        for (int i = 0; i < 4; ++i) {
            int idx = tid + i * 256;
            *(float4*)&sc[idx >> 6][(idx & 63) * 4] = rA[i];
        }
        *(float4*)&sx[tid >> 4][(tid & 15) * 4] = rB;
        __syncthreads();

        if (c0 + KC < Cdim) {   // prefetch next chunk into registers
            #pragma unroll
            for (int i = 0; i < 4; ++i) {
                int idx = tid + i * 256, r = idx >> 6, c4 = idx & 63;
                rA[i] = *(const float4*)(cb + (size_t)(c0 + KC + r) * Kdim + c4 * 4);
            }
            int r = tid >> 4, c4 = tid & 15;
            rB = *(const float4*)(xb + (size_t)(c0 + KC + r) * Ndim + n0 + c4 * 4);
        }

        // x-norm partials from staged tile (4 reads)
        #pragma unroll
        for (int r = 0; r < 4; ++r) {
            float v = sx[(tid >> 6) * 4 + r][tid & 63];
            xn2p = fmaf(v, v, xn2p);
        }

        // main 8x8 FMA tile (operands LDS-broadcast across lane groups)
        #pragma unroll
        for (int r = 0; r < KC; ++r) {
            float a0[8], b0[8];
            *(float4*)(a0)     = *(const float4*)&sc[r][kb];
            *(float4*)(a0 + 4) = *(const float4*)&sc[r][kb + 4];
            *(float4*)(b0)     = *(const float4*)&sx[r][nb];
            *(float4*)(b0 + 4) = *(const float4*)&sx[r][nb + 4];
            #pragma unroll
            for (int i = 0; i < 8; ++i)
                #pragma unroll
                for (int j = 0; j < 8; ++j)
                    acc[i][j] = fmaf(a0[i], b0[j], acc[i][j]);
        }
    }

    px[tid >> 6][tid & 63] = xn2p;
    __syncthreads();
    if (tid < NT) {
        float s = px[0][tid] + px[1][tid] + px[2][tid] + px[3][tid];
        invxS[tid] = 1.f / fmaxf(sqrtf(s), 1e-12f);
    }
    __syncthreads();

    const float alpha = alpha_p[0];
    const float beta  = beta_p[0];

    // per-thread argmax over its 8 k (ascending k, strict > = first-win),
    // sigmoid in fp32 per-k exactly like the reference
    #pragma unroll
    for (int j = 0; j < 8; ++j) {
        int n = nb + j;
        float ix = invxS[n];
        float best = -1.f; int bkk = 0;
        #pragma unroll
        for (int i = 0; i < 8; ++i) {
            float cosv = acc[i][j] * invcS[kb + i] * ix;
            float s = 1.f / (1.f + expf(-(beta + alpha * cosv)));
            if (s > best) { best = s; bkk = kb + i; }
        }
        bval[tid >> 3][n] = best;
        bidx[tid >> 3][n] = bkk;
    }
    __syncthreads();
    if (tid < NT) {
        int n = tid;
        float best = -1.f; int bkk = 0;
        for (int g = 0; g < 32; ++g) {   // ascending k-groups = first-win
            float v = bval[g][n];
            if (v > best) { best = v; bkk = bidx[g][n]; }
        }
        int gn = b * Ndim + n0 + n;
        wArr[gn] = best;
        kArr[gn] = bkk;
        simOut[((size_t)(b * Kdim + bkk)) * Ndim + n0 + n] = best;  // scatter
        atomicAdd(&cnt[b * Kdim + bkk], 1);
    }
}

// Kernel 2: per (b, 8 c-rows): stream all N tokens (float4 coalesced),
// LDS-atomic scatter into accs[c][k], fused (agg + ct)/(cnt+1) epilogue.
__global__ __launch_bounds__(256) void agg_kernel(
    const float* __restrict__ x,        // (B,C,N)
    const float* __restrict__ cents,    // (B,C,K)
    const float* __restrict__ wArr,
    const int*   __restrict__ kArr,
    const int*   __restrict__ cnt,
    float* __restrict__ hyp)            // (B,K,C)
{
    __shared__ float accs[CB][Kdim + 1];  // pad 257: conflict-free transpose
    __shared__ float wS[Ndim];            // 16 KB
    __shared__ int   kS[Ndim];            // 16 KB
    const int tid = threadIdx.x;
    const int b  = blockIdx.x / (Cdim / CB);
    const int c0 = (blockIdx.x % (Cdim / CB)) * CB;

    for (int i = tid; i < CB * (Kdim + 1); i += 256) ((float*)accs)[i] = 0.f;
    #pragma unroll
    for (int i = 0; i < Ndim / 4 / 256; ++i) {     // 4 float4 / int4 each
        int i4 = tid + i * 256;
        *(float4*)&wS[i4 * 4] = *(const float4*)&wArr[b * Ndim + i4 * 4];
        *(int4*)&kS[i4 * 4]   = *(const int4*)&kArr[b * Ndim + i4 * 4];
    }
    __syncthreads();

    const float* xb = x + (size_t)b * Cdim * Ndim;
    for (int r = 0; r < CB; ++r) {
        const float* row = xb + (size_t)(c0 + r) * Ndim;
        #pragma unroll
        for (int i = 0; i < Ndim / 4 / 256; ++i) {
            int i4 = tid + i * 256;
            float4 v = *(const float4*)&row[i4 * 4];
            int n = i4 * 4;
            atomicAdd(&accs[r][kS[n + 0]], wS[n + 0] * v.x);
            atomicAdd(&accs[r][kS[n + 1]], wS[n + 1] * v.y);
            atomicAdd(&accs[r][kS[n + 2]], wS[n + 2] * v.z);
            atomicAdd(&accs[r][kS[n + 3]], wS[n + 3] * v.w);
        }
    }
    __syncthreads();

    // fused epilogue: hyp[b][k][c0+cl] = (accs[cl][k] + cents[b][c0+cl][k]) / (cnt+1)
    const int cl = tid & 7;
    #pragma unroll
    for (int it = 0; it < 8; ++it) {
        int k = (tid >> 3) + it * 32;
        float num = accs[cl][k] + cents[((size_t)b * Cdim + c0 + cl) * Kdim + k];
        hyp[((size_t)(b * Kdim + k)) * Cdim + c0 + cl] = num / (float)(cnt[b * Kdim + k] + 1);
    }
}

extern "C" void kernel_launch(void* const* d_in, const int* in_sizes, int n_in,
                              void* d_out, int out_size, void* d_ws, size_t ws_size,
                              hipStream_t stream)
{
    const float* x     = (const float*)d_in[0];
    const float* cents = (const float*)d_in[1];
    const float* alpha = (const float*)d_in[2];
    const float* beta  = (const float*)d_in[3];

    float* hyp    = (float*)d_out;                                    // (B,K,C)
    float* simOut = (float*)d_out + (size_t)Bdim * Kdim * Cdim;       // (B,K,N)

    float* wArr = (float*)d_ws;
    int*   kArr = (int*)((char*)d_ws + (size_t)Bdim * Ndim * sizeof(float));
    int*   cnt  = (int*)((char*)d_ws + 2 * (size_t)Bdim * Ndim * sizeof(float));
    float* invc = (float*)((char*)d_ws + 2 * (size_t)Bdim * Ndim * sizeof(float)
                                       + (size_t)Bdim * Kdim * sizeof(int));

    hipMemsetAsync(simOut, 0, (size_t)Bdim * Kdim * Ndim * sizeof(float), stream);

    prep_kernel<<<dim3(Bdim), dim3(256), 0, stream>>>(cents, invc, cnt);
    sim_argmax_kernel<<<dim3(Bdim * (Ndim / NT)), dim3(256), 0, stream>>>(
        x, cents, alpha, beta, invc, simOut, wArr, kArr, cnt);
    agg_kernel<<<dim3(Bdim * (Cdim / CB)), dim3(256), 0, stream>>>(
        x, cents, wArr, kArr, cnt, hyp);
}

// Round 4
// 361.497 us; speedup vs baseline: 1.1031x; 1.0962x over previous
//
#include <hip/hip_runtime.h>
#include <cmath>

#define Bdim 8
#define Cdim 768
#define Kdim 256
#define Ndim 4096
#define NT 64      // tokens per block in kernel 1
#define KC 16      // C-chunk staged in LDS (double-buffered)
#define NCHUNK (Cdim / KC)
#define CB2 4      // c-rows per block in kernel 2

// direct global->LDS DMA, 16B per lane, wave-uniform LDS base
typedef __attribute__((address_space(1))) const unsigned int g_u32;
typedef __attribute__((address_space(3))) unsigned int l_u32;
__device__ __forceinline__ void gload16(const void* g, void* l) {
    __builtin_amdgcn_global_load_lds((g_u32*)g, (l_u32*)l, 16, 0, 0);
}

// Prep: per batch b — centroid inverse norms + zero cnt.
__global__ __launch_bounds__(256) void prep_kernel(
    const float* __restrict__ cents,   // (B,C,K)
    float* __restrict__ invc,          // (B,K)
    int*   __restrict__ cnt)           // (B,K)
{
    __shared__ float red[4][Kdim];
    const int tid = threadIdx.x;
    const int b = blockIdx.x;
    const float* cb = cents + (size_t)b * Cdim * Kdim;
    const int q = tid & 63;
    const int g = tid >> 6;
    float4 ss = make_float4(0.f, 0.f, 0.f, 0.f);
    for (int r = g; r < Cdim; r += 4) {
        float4 v = *(const float4*)(cb + (size_t)r * Kdim + q * 4);
        ss.x = fmaf(v.x, v.x, ss.x); ss.y = fmaf(v.y, v.y, ss.y);
        ss.z = fmaf(v.z, v.z, ss.z); ss.w = fmaf(v.w, v.w, ss.w);
    }
    *(float4*)&red[g][q * 4] = ss;
    __syncthreads();
    float s = red[0][tid] + red[1][tid] + red[2][tid] + red[3][tid];
    invc[b * Kdim + tid] = 1.f / fmaxf(sqrtf(s), 1e-12f);
    cnt[b * Kdim + tid] = 0;
}

// Kernel 1: per (b, n-tile of 64): fp32 cos GEMM (8x8/thread), sigmoid,
// first-win argmax, scatter winner into pre-zeroed simOut.
// Staging: global_load_lds DMA, double-buffered, 1 barrier per chunk.
__global__ __launch_bounds__(256) void sim_argmax_kernel(
    const float* __restrict__ x,        // (B,C,N)
    const float* __restrict__ cents,    // (B,C,K)
    const float* __restrict__ alpha_p,
    const float* __restrict__ beta_p,
    const float* __restrict__ invc,     // (B,K)
    float* __restrict__ simOut,         // (B,K,N), pre-zeroed
    float* __restrict__ wArr,           // (B,N)
    int*   __restrict__ kArr,           // (B,N)
    int*   __restrict__ cnt)            // (B,K), pre-zeroed
{
    __shared__ float sc[2][KC][Kdim];   // 32 KB centroid chunks (dbuf)
    __shared__ float sx[2][KC][NT];     // 8 KB  x chunks (dbuf)
    __shared__ float invcS[Kdim];       // 1 KB
    __shared__ float px[4][NT];         // 1 KB
    __shared__ float invxS[NT];
    __shared__ float bval[32][NT];      // 8 KB
    __shared__ int   bidx[32][NT];      // 8 KB

    const int tid  = threadIdx.x;
    const int lane = tid & 63;
    const int wv   = tid >> 6;          // wave id 0..3
    const int b    = blockIdx.x >> 6;
    const int n0   = (blockIdx.x & 63) * NT;
    const float* xb = x     + (size_t)b * Cdim * Ndim;
    const float* cb = cents + (size_t)b * Cdim * Kdim;

    invcS[tid] = invc[b * Kdim + tid];

    const int kb = (tid >> 3) * 8;
    const int nb = (tid & 7) * 8;

    float acc[8][8];
    #pragma unroll
    for (int i = 0; i < 8; ++i)
        #pragma unroll
        for (int j = 0; j < 8; ++j) acc[i][j] = 0.f;

    float xn2p = 0.f;

    // STAGE(chunk, buf): wave wv DMAs sc rows 4wv..4wv+3 (1 KB each) and
    // sx rows 4wv..4wv+3 (one 1 KB issue).  5 global_load_lds per wave.
    #define STAGE(ch, bf)                                                     \
        do {                                                                  \
            const int c0_ = (ch) * KC;                                        \
            _Pragma("unroll")                                                 \
            for (int i_ = 0; i_ < 4; ++i_) {                                  \
                int r_ = wv * 4 + i_;                                         \
                gload16(cb + (size_t)(c0_ + r_) * Kdim + lane * 4,            \
                        &sc[bf][r_][0]);                                      \
            }                                                                 \
            gload16(xb + (size_t)(c0_ + wv * 4 + (lane >> 4)) * Ndim          \
                       + n0 + (lane & 15) * 4,                                \
                    &sx[bf][wv * 4][0]);                                      \
        } while (0)

    STAGE(0, 0);
    __syncthreads();    // drains vmcnt(0): buf0 ready

    for (int t = 0; t < NCHUNK; ++t) {
        const int cur = t & 1;
        if (t + 1 < NCHUNK) STAGE(t + 1, cur ^ 1);   // async, hides under FMA

        // x-norm partials from staged tile
        #pragma unroll
        for (int r = 0; r < 4; ++r) {
            float v = sx[cur][(tid >> 6) * 4 + r][tid & 63];
            xn2p = fmaf(v, v, xn2p);
        }
        // 8x8 FMA tile
        #pragma unroll
        for (int r = 0; r < KC; ++r) {
            float a0[8], b0[8];
            *(float4*)(a0)     = *(const float4*)&sc[cur][r][kb];
            *(float4*)(a0 + 4) = *(const float4*)&sc[cur][r][kb + 4];
            *(float4*)(b0)     = *(const float4*)&sx[cur][r][nb];
            *(float4*)(b0 + 4) = *(const float4*)&sx[cur][r][nb + 4];
            #pragma unroll
            for (int i = 0; i < 8; ++i)
                #pragma unroll
                for (int j = 0; j < 8; ++j)
                    acc[i][j] = fmaf(a0[i], b0[j], acc[i][j]);
        }
        __syncthreads();   // readers done + next-chunk DMA drained
    }
    #undef STAGE

    px[tid >> 6][tid & 63] = xn2p;
    __syncthreads();
    if (tid < NT) {
        float s = px[0][tid] + px[1][tid] + px[2][tid] + px[3][tid];
        invxS[tid] = 1.f / fmaxf(sqrtf(s), 1e-12f);
    }
    __syncthreads();

    const float alpha = alpha_p[0];
    const float beta  = beta_p[0];

    #pragma unroll
    for (int j = 0; j < 8; ++j) {
        int n = nb + j;
        float ix = invxS[n];
        float best = -1.f; int bkk = 0;
        #pragma unroll
        for (int i = 0; i < 8; ++i) {
            float cosv = acc[i][j] * invcS[kb + i] * ix;
            float s = 1.f / (1.f + expf(-(beta + alpha * cosv)));
            if (s > best) { best = s; bkk = kb + i; }
        }
        bval[tid >> 3][n] = best;
        bidx[tid >> 3][n] = bkk;
    }
    __syncthreads();
    if (tid < NT) {
        int n = tid;
        float best = -1.f; int bkk = 0;
        for (int g = 0; g < 32; ++g) {   // ascending k-groups = first-win
            float v = bval[g][n];
            if (v > best) { best = v; bkk = bidx[g][n]; }
        }
        int gn = b * Ndim + n0 + n;
        wArr[gn] = best;
        kArr[gn] = bkk;
        simOut[((size_t)(b * Kdim + bkk)) * Ndim + n0 + n] = best;
        atomicAdd(&cnt[b * Kdim + bkk], 1);
    }
}

// Kernel 2: per (b, 4 c-rows): stream all N tokens; per token-quad read
// 4 rows' float4 (independent loads), 16 LDS-atomic adds; fused epilogue.
__global__ __launch_bounds__(256) void agg_kernel(
    const float* __restrict__ x,        // (B,C,N)
    const float* __restrict__ cents,    // (B,C,K)
    const float* __restrict__ wArr,
    const int*   __restrict__ kArr,
    const int*   __restrict__ cnt,
    float* __restrict__ hyp)            // (B,K,C)
{
    __shared__ float accs[CB2][Kdim + 1];       // 4.1 KB
    __shared__ float wS[Ndim];                  // 16 KB
    __shared__ unsigned char kS[Ndim];          // 4 KB (K=256 fits u8)
    const int tid = threadIdx.x;
    const int b  = blockIdx.x / (Cdim / CB2);
    const int c0 = (blockIdx.x % (Cdim / CB2)) * CB2;

    for (int i = tid; i < CB2 * (Kdim + 1); i += 256) ((float*)accs)[i] = 0.f;
    #pragma unroll
    for (int i = 0; i < 4; ++i) {
        int i4 = tid + i * 256;
        *(float4*)&wS[i4 * 4] = *(const float4*)&wArr[b * Ndim + i4 * 4];
        int4 kv = *(const int4*)&kArr[b * Ndim + i4 * 4];
        ((unsigned*)kS)[i4] = (unsigned)kv.x | ((unsigned)kv.y << 8) |
                              ((unsigned)kv.z << 16) | ((unsigned)kv.w << 24);
    }
    __syncthreads();

    const float* xb = x + ((size_t)b * Cdim + c0) * Ndim;
    #pragma unroll
    for (int i = 0; i < 4; ++i) {
        int i4 = tid + i * 256;
        int n = i4 * 4;
        float4 xv[CB2];
        #pragma unroll
        for (int r = 0; r < CB2; ++r)
            xv[r] = *(const float4*)&xb[(size_t)r * Ndim + n];
        float4 w4 = *(float4*)&wS[n];
        unsigned kw = ((unsigned*)kS)[i4];
        int k0 = kw & 255, k1 = (kw >> 8) & 255, k2 = (kw >> 16) & 255, k3 = kw >> 24;
        #pragma unroll
        for (int r = 0; r < CB2; ++r) {
            atomicAdd(&accs[r][k0], w4.x * xv[r].x);
            atomicAdd(&accs[r][k1], w4.y * xv[r].y);
            atomicAdd(&accs[r][k2], w4.z * xv[r].z);
            atomicAdd(&accs[r][k3], w4.w * xv[r].w);
        }
    }
    __syncthreads();

    // fused epilogue: hyp[b][k][c0+cl] = (accs[cl][k] + ct)/(cnt+1)
    const int cl = tid & 3;
    #pragma unroll
    for (int it = 0; it < 4; ++it) {
        int k = (tid >> 2) + it * 64;
        float num = accs[cl][k] + cents[((size_t)b * Cdim + c0 + cl) * Kdim + k];
        hyp[((size_t)(b * Kdim + k)) * Cdim + c0 + cl] = num / (float)(cnt[b * Kdim + k] + 1);
    }
}

extern "C" void kernel_launch(void* const* d_in, const int* in_sizes, int n_in,
                              void* d_out, int out_size, void* d_ws, size_t ws_size,
                              hipStream_t stream)
{
    const float* x     = (const float*)d_in[0];
    const float* cents = (const float*)d_in[1];
    const float* alpha = (const float*)d_in[2];
    const float* beta  = (const float*)d_in[3];

    float* hyp    = (float*)d_out;                                    // (B,K,C)
    float* simOut = (float*)d_out + (size_t)Bdim * Kdim * Cdim;       // (B,K,N)

    float* wArr = (float*)d_ws;
    int*   kArr = (int*)((char*)d_ws + (size_t)Bdim * Ndim * sizeof(float));
    int*   cnt  = (int*)((char*)d_ws + 2 * (size_t)Bdim * Ndim * sizeof(float));
    float* invc = (float*)((char*)d_ws + 2 * (size_t)Bdim * Ndim * sizeof(float)
                                       + (size_t)Bdim * Kdim * sizeof(int));

    hipMemsetAsync(simOut, 0, (size_t)Bdim * Kdim * Ndim * sizeof(float), stream);

    prep_kernel<<<dim3(Bdim), dim3(256), 0, stream>>>(cents, invc, cnt);
    sim_argmax_kernel<<<dim3(Bdim * (Ndim / NT)), dim3(256), 0, stream>>>(
        x, cents, alpha, beta, invc, simOut, wArr, kArr, cnt);
    agg_kernel<<<dim3(Bdim * (Cdim / CB2)), dim3(256), 0, stream>>>(
        x, cents, wArr, kArr, cnt, hyp);
}